// Round 3
// baseline (349.286 us; speedup 1.0000x reference)
//
#include <hip/hip_runtime.h>
#include <hip/hip_bf16.h>
#include <math.h>

typedef float floatx16 __attribute__((ext_vector_type(16)));
typedef __bf16 bf16x8 __attribute__((ext_vector_type(8)));

#define SEQ 2048
#define NH 8
#define DH 64
#define HEADS 16
#define RS (NH * DH)   // 512 floats between consecutive sequence positions

__device__ __forceinline__ unsigned int pk2bf(float a, float b) {
  union { __hip_bfloat162 h2; unsigned int u; } c;
  c.h2 = __float22bfloat162_rn(make_float2(a, b));
  return c.u;
}

// v_permlane32_swap_b32, orientation probed at runtime (R12-verified).
__device__ __forceinline__ void hswap_fwd(unsigned& a, unsigned& b) {
  asm volatile("v_permlane32_swap_b32 %0, %1" : "+v"(a), "+v"(b));
}
__device__ __forceinline__ void hswap_rev(unsigned& a, unsigned& b) {
  asm volatile("v_permlane32_swap_b32 %0, %1" : "+v"(b), "+v"(a));
}

// ---- fused attention, register-pipelined (R3).
//      R2 post-mortem: WRITE_SIZE 8MB->306MB with VGPR pinned at 128 = scratch
//      spill storm. Cause: vB[cb] runtime-indexed when the big loop failed to
//      unroll (ext_vector arrays with dynamic index -> scratch), plus
//      __launch_bounds__(512,2) boxing the allocator (documented R5/R6 trap).
//      Fix: TWO NAMED buffers vCur/vNxt (statically indexed no matter what the
//      unroller does), 2 iterations per loop step with explicit buffer roles,
//      and no launch_bounds occupancy floor. V(it+1) is issued before iter it's
//      K-loads + 32 MFMA + 64 exp2, pulling the scattered 2KB-stride V dword
//      loads (R1's dominant latency) off the critical path.
#define SMEM_BYTES 37376   // oM [8][16][72]*4 = 36864 + lM [8][16]*4 = 512

__global__ __launch_bounds__(512)
void attn(const float* __restrict__ q, const float* __restrict__ k,
          const float* __restrict__ v, float* __restrict__ out) {
  __shared__ __align__(16) char smem[SMEM_BYTES];
  float* oM = (float*)smem;                             // [8][16][72]
  float* lM = (float*)(smem + 8 * 16 * 72 * 4);         // [8][16]

  const int tid  = threadIdx.x;
  const int wave = tid >> 6;
  const int lane = tid & 63;
  const int l32  = lane & 31;
  const int hl   = lane >> 5;
  const int wq   = wave >> 2;        // q-half (0/1)
  const int wk   = wave & 3;         // key-quarter (0..3)

  // probe permlane32_swap orientation (wave-uniform)
  unsigned px = (unsigned)lane, py = (unsigned)lane + 100u;
  hswap_fwd(px, py);
  const bool mir = (__builtin_amdgcn_readfirstlane(px) != 0u);

  const int bx   = blockIdx.x;
  const int head = bx & 15;          // XCD h%8 affinity (16 blocks/head share L2)
  const int qh2  = bx >> 4;          // 0..15, 128 q-rows per block
  const int n = head >> 3, h = head & 7;

  const float* kf = k + ((size_t)n * SEQ * NH + h) * DH;
  const float* vf = v + ((size_t)n * SEQ * NH + h) * DH;

  // wave-uniform quarter bases (SGPR); per-lane element offsets separate
  const int swk = __builtin_amdgcn_readfirstlane(wk);
  const float* kq = kf + (size_t)swk * 8 * 64 * RS;
  const float* vq = vf + (size_t)swk * 8 * 64 * RS;
  const int klane = l32 * RS + hl * 8;       // K frag: row=l32(+ks2*32), col base=hl*8
  const int vlane = hl * 8 * RS + l32;       // V frag: s base=hl*8, d=l32(+dsub*32)

  // Q B-fragments: lane holds Q[q = qh2*128 + wq*64 + qs*32 + l32][d = kk*16 + hl*8 + j]
  bf16x8 qB[2][4];
  #pragma unroll
  for (int qs = 0; qs < 2; ++qs)
    #pragma unroll
    for (int kk = 0; kk < 4; ++kk) {
      const int row = qh2 * 128 + wq * 64 + qs * 32 + l32;
      const float* src = q + ((size_t)((n * SEQ + row) * NH + h)) * DH + kk * 16 + hl * 8;
      float4 x0 = *(const float4*)src;
      float4 x1 = *(const float4*)(src + 4);
      union { unsigned int u32[4]; bf16x8 v8; } u;
      u.u32[0] = pk2bf(x0.x, x0.y); u.u32[1] = pk2bf(x0.z, x0.w);
      u.u32[2] = pk2bf(x1.x, x1.y); u.u32[3] = pk2bf(x1.z, x1.w);
      qB[qs][kk] = u.v8;
    }

  floatx16 o[2][2];
  float lsum[2];
  #pragma unroll
  for (int qs = 0; qs < 2; ++qs) {
    lsum[qs] = 0.f;
    #pragma unroll
    for (int d = 0; d < 2; ++d)
      #pragma unroll
      for (int i = 0; i < 16; ++i) o[qs][d][i] = 0.f;
  }

  const float S = 0.125f * 1.4426950408889634f;
  const float C = 12.0f;

  // V fragment loader: lane holds V[s = itv*64 + ss*16 + hl*8 + j][d = dsub*32 + l32]
  auto loadV = [&](bf16x8 (&dst)[4][2], int itv) {
    #pragma unroll
    for (int ss = 0; ss < 4; ++ss)
      #pragma unroll
      for (int dsub = 0; dsub < 2; ++dsub) {
        const float* src = vq + itv * 64 * RS + ss * 16 * RS + vlane + dsub * 32;
        float w0 = src[0 * RS], w1 = src[1 * RS], w2 = src[2 * RS], w3 = src[3 * RS];
        float w4 = src[4 * RS], w5 = src[5 * RS], w6 = src[6 * RS], w7 = src[7 * RS];
        union { unsigned int u32[4]; bf16x8 v8; } u;
        u.u32[0] = pk2bf(w0, w1); u.u32[1] = pk2bf(w2, w3);
        u.u32[2] = pk2bf(w4, w5); u.u32[3] = pk2bf(w6, w7);
        dst[ss][dsub] = u.v8;
      }
  };

  // one 64-key tile: K loads + QK^T + softmax + PV, consuming vb
  auto body = [&](int it, bf16x8 (&vb)[4][2]) {
    bf16x8 kA[2][4];
    #pragma unroll
    for (int ks2 = 0; ks2 < 2; ++ks2)
      #pragma unroll
      for (int kk = 0; kk < 4; ++kk) {
        const float* src = kq + it * 64 * RS + ks2 * 32 * RS + klane + kk * 16;
        float4 x0 = *(const float4*)src;
        float4 x1 = *(const float4*)(src + 4);
        union { unsigned int u32[4]; bf16x8 v8; } u;
        u.u32[0] = pk2bf(x0.x, x0.y); u.u32[1] = pk2bf(x0.z, x0.w);
        u.u32[2] = pk2bf(x1.x, x1.y); u.u32[3] = pk2bf(x1.z, x1.w);
        kA[ks2][kk] = u.v8;
      }

    #pragma unroll
    for (int ks2 = 0; ks2 < 2; ++ks2) {
      floatx16 acc2[2];
      #pragma unroll
      for (int i = 0; i < 16; ++i) acc2[0][i] = 0.f;
      #pragma unroll
      for (int kk = 0; kk < 4; ++kk)
        acc2[0] = __builtin_amdgcn_mfma_f32_32x32x16_bf16(kA[ks2][kk], qB[0][kk], acc2[0], 0, 0, 0);

      #pragma unroll
      for (int m = 0; m < 2; ++m) {
        unsigned pkv[8];
        #pragma unroll
        for (int g2 = 0; g2 < 4; ++g2) {
          float p0 = __builtin_amdgcn_exp2f(acc2[m][4 * g2 + 0] * S - C);
          float p1 = __builtin_amdgcn_exp2f(acc2[m][4 * g2 + 1] * S - C);
          float p2 = __builtin_amdgcn_exp2f(acc2[m][4 * g2 + 2] * S - C);
          float p3 = __builtin_amdgcn_exp2f(acc2[m][4 * g2 + 3] * S - C);
          lsum[m] += (p0 + p1) + (p2 + p3);
          pkv[g2 * 2]     = pk2bf(p0, p1);
          pkv[g2 * 2 + 1] = pk2bf(p2, p3);
        }

        if (m == 0) {
          #pragma unroll
          for (int i = 0; i < 16; ++i) acc2[1][i] = 0.f;
          #pragma unroll
          for (int kk = 0; kk < 4; ++kk)
            acc2[1] = __builtin_amdgcn_mfma_f32_32x32x16_bf16(kA[ks2][kk], qB[1][kk], acc2[1], 0, 0, 0);
        }

        union { unsigned u32[4]; bf16x8 v8; } A1, A2;
        A1.u32[0] = pkv[0]; A1.u32[2] = pkv[2];
        A1.u32[1] = pkv[1]; A1.u32[3] = pkv[3];
        A2.u32[0] = pkv[4]; A2.u32[2] = pkv[6];
        A2.u32[1] = pkv[5]; A2.u32[3] = pkv[7];
        if (!mir) {
          hswap_fwd(A1.u32[0], A1.u32[2]); hswap_fwd(A1.u32[1], A1.u32[3]);
          hswap_fwd(A2.u32[0], A2.u32[2]); hswap_fwd(A2.u32[1], A2.u32[3]);
        } else {
          hswap_rev(A1.u32[0], A1.u32[2]); hswap_rev(A1.u32[1], A1.u32[3]);
          hswap_rev(A2.u32[0], A2.u32[2]); hswap_rev(A2.u32[1], A2.u32[3]);
        }

        o[m][0] = __builtin_amdgcn_mfma_f32_32x32x16_bf16(A1.v8, vb[ks2 * 2][0],     o[m][0], 0, 0, 0);
        o[m][1] = __builtin_amdgcn_mfma_f32_32x32x16_bf16(A1.v8, vb[ks2 * 2][1],     o[m][1], 0, 0, 0);
        o[m][0] = __builtin_amdgcn_mfma_f32_32x32x16_bf16(A2.v8, vb[ks2 * 2 + 1][0], o[m][0], 0, 0, 0);
        o[m][1] = __builtin_amdgcn_mfma_f32_32x32x16_bf16(A2.v8, vb[ks2 * 2 + 1][1], o[m][1], 0, 0, 0);
      }
    }
  };

  // ---- software pipeline: two NAMED register buffers, 2 tiles per step ----
  bf16x8 vCur[4][2], vNxt[4][2];
  loadV(vCur, 0);
  #pragma unroll
  for (int it2 = 0; it2 < 4; ++it2) {
    loadV(vNxt, 2 * it2 + 1);          // prefetch odd tile
    body(2 * it2, vCur);               // compute even tile
    if (it2 < 3) loadV(vCur, 2 * it2 + 2);  // prefetch next even tile
    body(2 * it2 + 1, vNxt);           // compute odd tile
  }

  // lsum: lanes L and L+32 hold disjoint key subsets of the same q
  #pragma unroll
  for (int qs = 0; qs < 2; ++qs)
    lsum[qs] += __shfl_xor(lsum[qs], 32, 64);

  // ---- 4-phase merge: sum the 4 key-quarter waves of each q-half ----
  const int r32  = tid >> 4;          // 0..31 row-slot
  const int wqr  = r32 >> 4;          // which q-half this thread merges
  const int prow = r32 & 15;          // row within phase group
  const int col4 = tid & 15;          // float4 column
  #pragma unroll
  for (int p = 0; p < 4; ++p) {
    const int qsub = p >> 1, rh = p & 1;
    __syncthreads();
    #pragma unroll
    for (int r8 = 0; r8 < 8; ++r8) {
      const int r   = rh * 8 + r8;
      const int rip = (r8 & 3) + 4 * hl + 8 * (r8 >> 2);   // row in phase, 0..15
      oM[(wave * 16 + rip) * 72 + l32]      = o[qsub][0][r];
      oM[(wave * 16 + rip) * 72 + 32 + l32] = o[qsub][1][r];
    }
    if (lane < 32 && ((lane >> 4) & 1) == rh) lM[wave * 16 + (lane & 15)] = lsum[qsub];
    __syncthreads();
    float4 s = make_float4(0.f, 0.f, 0.f, 0.f);
    float l = 0.f;
    #pragma unroll
    for (int j = 0; j < 4; ++j) {
      const int w = wqr * 4 + j;
      float4 t4 = *(const float4*)&oM[(w * 16 + prow) * 72 + col4 * 4];
      s.x += t4.x; s.y += t4.y; s.z += t4.z; s.w += t4.w;
      l += lM[w * 16 + prow];
    }
    float inv = 1.f / l;
    const int grow = qh2 * 128 + wqr * 64 + p * 16 + prow;
    float4 st; st.x = s.x * inv; st.y = s.y * inv; st.z = s.z * inv; st.w = s.w * inv;
    *(float4*)(out + ((size_t)((n * SEQ + grow) * NH + h)) * DH + col4 * 4) = st;
  }
}

extern "C" void kernel_launch(void* const* d_in, const int* in_sizes, int n_in,
                              void* d_out, int out_size, void* d_ws, size_t ws_size,
                              hipStream_t stream) {
  const float* q = (const float*)d_in[0];
  const float* k = (const float*)d_in[1];
  const float* v = (const float*)d_in[2];
  float* out = (float*)d_out;
  (void)in_sizes; (void)n_in; (void)out_size; (void)d_ws; (void)ws_size;

  attn<<<HEADS * (SEQ / 128), 512, 0, stream>>>(q, k, v, out);
}

// Round 4
// 111.744 us; speedup vs baseline: 3.1258x; 3.1258x over previous
//
#include <hip/hip_runtime.h>
#include <hip/hip_bf16.h>
#include <math.h>

typedef float floatx16 __attribute__((ext_vector_type(16)));
typedef __bf16 bf16x8 __attribute__((ext_vector_type(8)));

#define SEQ 2048
#define NH 8
#define DH 64
#define NB 2
#define HEADS 16
#define HSTRIDE (SEQ * DH)       // per-head elems in packed tensors (131072)
#define TILE_E (64 * 64)         // elems per 64-key tile

__device__ __forceinline__ unsigned short f2bf(float x) {
  union { __bf16 b; unsigned short u; } c; c.b = (__bf16)x; return c.u;
}
__device__ __forceinline__ unsigned int pk2bf(float a, float b) {
  union { __hip_bfloat162 h2; unsigned int u; } c;
  c.h2 = __float22bfloat162_rn(make_float2(a, b));
  return c.u;
}

// v_permlane32_swap_b32, orientation probed at runtime (R12-verified).
__device__ __forceinline__ void hswap_fwd(unsigned& a, unsigned& b) {
  asm volatile("v_permlane32_swap_b32 %0, %1" : "+v"(a), "+v"(b));
}
__device__ __forceinline__ void hswap_rev(unsigned& a, unsigned& b) {
  asm volatile("v_permlane32_swap_b32 %0, %1" : "+v"(b), "+v"(a));
}

// ---- pre-pass: K,V fp32 [n,s,h,d] -> bf16 in 32x32x16-MFMA fragment order ----
// (verbatim from the verified 100.9us session kernel; XCD affinity head=bx&15)
__global__ __launch_bounds__(256)
void pack_kv(const float* __restrict__ k, const float* __restrict__ v,
             unsigned short* __restrict__ kb, unsigned short* __restrict__ vb) {
  __shared__ unsigned short Ts[64][68];   // V tile [s][d]
  const int tid  = threadIdx.x;
  const int bx   = blockIdx.x;
  const int head = bx & 15;
  const int kt   = bx >> 4;
  const int n = head >> 3, h = head & 7;

  #pragma unroll
  for (int j2 = 0; j2 < 2; ++j2) {
    int c = j2 * 256 + tid;
    int lane = c & 63;
    int kk = (c >> 6) & 3, ks2 = c >> 8;
    int row = kt * 64 + ks2 * 32 + (lane & 31);
    int d0  = kk * 16 + (lane >> 5) * 8;
    const float* src = k + ((size_t)(n * SEQ + row) * NH + h) * DH + d0;
    float4 a = *(const float4*)src;
    float4 b = *(const float4*)(src + 4);
    ushort4 lo, hi;
    lo.x = f2bf(a.x); lo.y = f2bf(a.y); lo.z = f2bf(a.z); lo.w = f2bf(a.w);
    hi.x = f2bf(b.x); hi.y = f2bf(b.y); hi.z = f2bf(b.z); hi.w = f2bf(b.w);
    unsigned short* dst = kb + (size_t)head * HSTRIDE + kt * TILE_E + c * 8;
    *(ushort4*)dst = lo;
    *(ushort4*)(dst + 4) = hi;
  }

  #pragma unroll
  for (int i = 0; i < 4; ++i) {
    int id = i * 256 + tid;
    int s  = id >> 4;
    int c4 = (id & 15) * 4;
    size_t g = ((size_t)((n * SEQ + kt * 64 + s) * NH + h)) * DH + c4;
    float4 x = *(const float4*)(v + g);
    ushort4 y;
    y.x = f2bf(x.x); y.y = f2bf(x.y); y.z = f2bf(x.z); y.w = f2bf(x.w);
    *(ushort4*)&Ts[s][c4] = y;
  }
  __syncthreads();
  #pragma unroll
  for (int j2 = 0; j2 < 2; ++j2) {
    int c = j2 * 256 + tid;
    int lane = c & 63;
    int dsub = (c >> 6) & 1, ss = c >> 7;
    int s0 = ss * 16 + (lane >> 5) * 8;
    int d  = dsub * 32 + (lane & 31);
    ushort4 lo, hi;
    lo.x = Ts[s0 + 0][d]; lo.y = Ts[s0 + 1][d]; lo.z = Ts[s0 + 2][d]; lo.w = Ts[s0 + 3][d];
    hi.x = Ts[s0 + 4][d]; hi.y = Ts[s0 + 5][d]; hi.z = Ts[s0 + 6][d]; hi.w = Ts[s0 + 7][d];
    unsigned short* dst = vb + (size_t)head * HSTRIDE + kt * TILE_E + c * 8;
    *(ushort4*)dst = lo;
    *(ushort4*)(dst + 4) = hi;
  }
}

// ---- attention, occupancy-optimized (R4).
//      R2/R3 post-mortem: in-wave V double-buffering spills (live set already
//      ~190 unified regs at 64 q-rows/wave; +64 regs -> scratch storm, 300MB
//      writes). Lever abandoned. Instead: shrink per-wave state to <=128 regs
//      (32 q-rows/wave: o 32, qB 16, acc 16; K/V frags loaded per-ks2) so
//      4 waves/SIMD fit. Blocks: 256 thr / 4 waves (4-way key split), grid
//      1024 = 4 blocks/CU, one residency round, 16 waves/CU = 2x the latency
//      hiding of R0/R1. KV re-read 2x more but all L2-resident (~2.5 of
//      4.3 TB/s per XCD). Packed bf16 KV (pack_kv) restored: 16 vector loads
//      per tile, zero cvt VALU in the hot loop.
#define SMEM_BYTES (4 * 16 * 72 * 4 + 4 * 16 * 4)   // oM 18432 + lM 256

__global__ __launch_bounds__(256, 4)
void attn(const float* __restrict__ q, const unsigned short* __restrict__ kb,
          const unsigned short* __restrict__ vt, float* __restrict__ out) {
  __shared__ __align__(16) char smem[SMEM_BYTES];
  float* oM = (float*)smem;                             // [4][16][72]
  float* lM = (float*)(smem + 4 * 16 * 72 * 4);         // [4][16]

  const int tid  = threadIdx.x;
  const int wave = tid >> 6;
  const int lane = tid & 63;
  const int l32  = lane & 31;
  const int hl   = lane >> 5;

  // probe permlane32_swap orientation (wave-uniform)
  unsigned px = (unsigned)lane, py = (unsigned)lane + 100u;
  hswap_fwd(px, py);
  const bool mir = (__builtin_amdgcn_readfirstlane(px) != 0u);

  const int bx   = blockIdx.x;
  const int head = bx & 15;          // XCD h%8 affinity — matches pack's writes
  const int qc   = bx >> 4;          // 0..63, 32 q-rows per block
  const int n = head >> 3, h = head & 7;

  const int swk = __builtin_amdgcn_readfirstlane(wave);   // key-quarter, SGPR
  const unsigned short* kq = kb + (size_t)head * HSTRIDE + (size_t)swk * 8 * TILE_E;
  const unsigned short* vq = vt + (size_t)head * HSTRIDE + (size_t)swk * 8 * TILE_E;

  // Q B-fragments: lane holds Q[q = qc*32 + l32][d = kk*16 + hl*8 + j]
  bf16x8 qB[4];
  #pragma unroll
  for (int kk = 0; kk < 4; ++kk) {
    const int row = qc * 32 + l32;
    const float* src = q + ((size_t)((n * SEQ + row) * NH + h)) * DH + kk * 16 + hl * 8;
    float4 x0 = *(const float4*)src;
    float4 x1 = *(const float4*)(src + 4);
    union { unsigned int u32[4]; bf16x8 v8; } u;
    u.u32[0] = pk2bf(x0.x, x0.y); u.u32[1] = pk2bf(x0.z, x0.w);
    u.u32[2] = pk2bf(x1.x, x1.y); u.u32[3] = pk2bf(x1.z, x1.w);
    qB[kk] = u.v8;
  }

  floatx16 o[2];
  float lsum = 0.f;
  #pragma unroll
  for (int d = 0; d < 2; ++d)
    #pragma unroll
    for (int i = 0; i < 16; ++i) o[d][i] = 0.f;

  const float S = 0.125f * 1.4426950408889634f;
  const float C = 12.0f;

  for (int it = 0; it < 8; ++it) {
    const unsigned short* tb_k = kq + it * TILE_E;
    const unsigned short* tb_v = vq + it * TILE_E;

    // issue order = consumption order: kA0 (QK0), vb0 (PV0), kA1 (QK1)
    bf16x8 kA0[4], kA1[4];
    bf16x8 vb0[2][2], vb1[2][2];
    #pragma unroll
    for (int kk = 0; kk < 4; ++kk)
      kA0[kk] = *(const bf16x8*)(tb_k + (kk * 64 + lane) * 8);
    #pragma unroll
    for (int j = 0; j < 2; ++j)
      #pragma unroll
      for (int d = 0; d < 2; ++d)
        vb0[j][d] = *(const bf16x8*)(tb_v + ((j * 2 + d) * 64 + lane) * 8);
    #pragma unroll
    for (int kk = 0; kk < 4; ++kk)
      kA1[kk] = *(const bf16x8*)(tb_k + ((4 + kk) * 64 + lane) * 8);

    // ---- ks2 = 0 ----
    floatx16 acc;
    #pragma unroll
    for (int i = 0; i < 16; ++i) acc[i] = 0.f;
    #pragma unroll
    for (int kk = 0; kk < 4; ++kk)
      acc = __builtin_amdgcn_mfma_f32_32x32x16_bf16(kA0[kk], qB[kk], acc, 0, 0, 0);

    {
      unsigned pkv[8];
      #pragma unroll
      for (int g2 = 0; g2 < 4; ++g2) {
        float p0 = __builtin_amdgcn_exp2f(acc[4 * g2 + 0] * S - C);
        float p1 = __builtin_amdgcn_exp2f(acc[4 * g2 + 1] * S - C);
        float p2 = __builtin_amdgcn_exp2f(acc[4 * g2 + 2] * S - C);
        float p3 = __builtin_amdgcn_exp2f(acc[4 * g2 + 3] * S - C);
        lsum += (p0 + p1) + (p2 + p3);
        pkv[g2 * 2]     = pk2bf(p0, p1);
        pkv[g2 * 2 + 1] = pk2bf(p2, p3);
      }
      // issue V for ks2=1 now — consumed after QK1+softmax1 (max cover)
      #pragma unroll
      for (int j = 0; j < 2; ++j)
        #pragma unroll
        for (int d = 0; d < 2; ++d)
          vb1[j][d] = *(const bf16x8*)(tb_v + (((2 + j) * 2 + d) * 64 + lane) * 8);

      union { unsigned u32[4]; bf16x8 v8; } A1, A2;
      A1.u32[0] = pkv[0]; A1.u32[2] = pkv[2];
      A1.u32[1] = pkv[1]; A1.u32[3] = pkv[3];
      A2.u32[0] = pkv[4]; A2.u32[2] = pkv[6];
      A2.u32[1] = pkv[5]; A2.u32[3] = pkv[7];
      if (!mir) {
        hswap_fwd(A1.u32[0], A1.u32[2]); hswap_fwd(A1.u32[1], A1.u32[3]);
        hswap_fwd(A2.u32[0], A2.u32[2]); hswap_fwd(A2.u32[1], A2.u32[3]);
      } else {
        hswap_rev(A1.u32[0], A1.u32[2]); hswap_rev(A1.u32[1], A1.u32[3]);
        hswap_rev(A2.u32[0], A2.u32[2]); hswap_rev(A2.u32[1], A2.u32[3]);
      }
      o[0] = __builtin_amdgcn_mfma_f32_32x32x16_bf16(A1.v8, vb0[0][0], o[0], 0, 0, 0);
      o[1] = __builtin_amdgcn_mfma_f32_32x32x16_bf16(A1.v8, vb0[0][1], o[1], 0, 0, 0);
      o[0] = __builtin_amdgcn_mfma_f32_32x32x16_bf16(A2.v8, vb0[1][0], o[0], 0, 0, 0);
      o[1] = __builtin_amdgcn_mfma_f32_32x32x16_bf16(A2.v8, vb0[1][1], o[1], 0, 0, 0);
    }

    // ---- ks2 = 1 ----
    #pragma unroll
    for (int i = 0; i < 16; ++i) acc[i] = 0.f;
    #pragma unroll
    for (int kk = 0; kk < 4; ++kk)
      acc = __builtin_amdgcn_mfma_f32_32x32x16_bf16(kA1[kk], qB[kk], acc, 0, 0, 0);

    {
      unsigned pkv[8];
      #pragma unroll
      for (int g2 = 0; g2 < 4; ++g2) {
        float p0 = __builtin_amdgcn_exp2f(acc[4 * g2 + 0] * S - C);
        float p1 = __builtin_amdgcn_exp2f(acc[4 * g2 + 1] * S - C);
        float p2 = __builtin_amdgcn_exp2f(acc[4 * g2 + 2] * S - C);
        float p3 = __builtin_amdgcn_exp2f(acc[4 * g2 + 3] * S - C);
        lsum += (p0 + p1) + (p2 + p3);
        pkv[g2 * 2]     = pk2bf(p0, p1);
        pkv[g2 * 2 + 1] = pk2bf(p2, p3);
      }
      union { unsigned u32[4]; bf16x8 v8; } A1, A2;
      A1.u32[0] = pkv[0]; A1.u32[2] = pkv[2];
      A1.u32[1] = pkv[1]; A1.u32[3] = pkv[3];
      A2.u32[0] = pkv[4]; A2.u32[2] = pkv[6];
      A2.u32[1] = pkv[5]; A2.u32[3] = pkv[7];
      if (!mir) {
        hswap_fwd(A1.u32[0], A1.u32[2]); hswap_fwd(A1.u32[1], A1.u32[3]);
        hswap_fwd(A2.u32[0], A2.u32[2]); hswap_fwd(A2.u32[1], A2.u32[3]);
      } else {
        hswap_rev(A1.u32[0], A1.u32[2]); hswap_rev(A1.u32[1], A1.u32[3]);
        hswap_rev(A2.u32[0], A2.u32[2]); hswap_rev(A2.u32[1], A2.u32[3]);
      }
      o[0] = __builtin_amdgcn_mfma_f32_32x32x16_bf16(A1.v8, vb1[0][0], o[0], 0, 0, 0);
      o[1] = __builtin_amdgcn_mfma_f32_32x32x16_bf16(A1.v8, vb1[0][1], o[1], 0, 0, 0);
      o[0] = __builtin_amdgcn_mfma_f32_32x32x16_bf16(A2.v8, vb1[1][0], o[0], 0, 0, 0);
      o[1] = __builtin_amdgcn_mfma_f32_32x32x16_bf16(A2.v8, vb1[1][1], o[1], 0, 0, 0);
    }
  }

  // lanes L and L+32 hold disjoint key subsets of the same q-row
  lsum += __shfl_xor(lsum, 32, 64);

  // ---- 2-phase merge: sum the 4 key-quarter waves ----
  const int prow = tid >> 4;          // 0..15 row within phase
  const int col4 = tid & 15;          // float4 column
  #pragma unroll
  for (int p = 0; p < 2; ++p) {
    const int rh = p;
    __syncthreads();
    #pragma unroll
    for (int r8 = 0; r8 < 8; ++r8) {
      const int r   = rh * 8 + r8;
      const int rip = (r8 & 3) + 4 * hl + 8 * (r8 >> 2);   // row in phase, 0..15
      oM[(wave * 16 + rip) * 72 + l32]      = o[0][r];
      oM[(wave * 16 + rip) * 72 + 32 + l32] = o[1][r];
    }
    if (lane < 32 && ((lane >> 4) & 1) == rh) lM[wave * 16 + (lane & 15)] = lsum;
    __syncthreads();
    float4 s = make_float4(0.f, 0.f, 0.f, 0.f);
    float l = 0.f;
    #pragma unroll
    for (int w = 0; w < 4; ++w) {
      float4 t4 = *(const float4*)&oM[(w * 16 + prow) * 72 + col4 * 4];
      s.x += t4.x; s.y += t4.y; s.z += t4.z; s.w += t4.w;
      l += lM[w * 16 + prow];
    }
    float inv = 1.f / l;
    const int grow = qc * 32 + p * 16 + prow;
    float4 st; st.x = s.x * inv; st.y = s.y * inv; st.z = s.z * inv; st.w = s.w * inv;
    *(float4*)(out + ((size_t)((n * SEQ + grow) * NH + h)) * DH + col4 * 4) = st;
  }
}

extern "C" void kernel_launch(void* const* d_in, const int* in_sizes, int n_in,
                              void* d_out, int out_size, void* d_ws, size_t ws_size,
                              hipStream_t stream) {
  const float* q = (const float*)d_in[0];
  const float* k = (const float*)d_in[1];
  const float* v = (const float*)d_in[2];
  float* out = (float*)d_out;
  (void)in_sizes; (void)n_in; (void)out_size; (void)ws_size;

  unsigned short* kb = (unsigned short*)d_ws;                       // 4 MB
  unsigned short* vb = kb + (size_t)HEADS * HSTRIDE;                // 4 MB

  pack_kv<<<HEADS * (SEQ / 64), 256, 0, stream>>>(k, v, kb, vb);
  attn<<<HEADS * (SEQ / 32), 256, 0, stream>>>(q, kb, vb, out);
}